// Round 3
// baseline (145.172 us; speedup 1.0000x reference)
//
#include <hip/hip_runtime.h>
#include <hip/hip_bf16.h>

// RuleNBFNet: B=8, D=64, H=3, R2=12, Rn=1728.  Inputs f32, output f32.
// R13: 3-kernel pipeline: k_pre (pre-role: Wt2/relT2/QW1 blocks || mid-role:
// self-sufficient k_mid blocks that fold Wt0/1 into 128KB LDS and compute
// their own relT0/1) -> k_score -> k_final.  Removes one launch gap and the
// k_pre1->k_mid serialization (mid blocks no longer depend on a prior kernel).
// Feature algebra: m=q*rel, p=max(m,0), n=min(m,0):
//   0.5m*W0 + p*W1 + n*W2 + max(0.5|m|,1e-3)*W3
//     = p*A + n*Bc + max(|m|,2e-3)*Wz'   with A=0.5W0+W1, Bc=0.5W0+W2, Wz'=0.5W3
// R11 refold: p*A + n*Bc = m*A' + |m|*B'  with A'=(A+Bc)/2, B'=(A-Bc)/2.
// R12: m,t=max(|m|,2e-3) are lane-invariant -> hoisted per-wave into LDS;
//   inner loop = 3 fma per (rule,d) + broadcast ds_read_b128.
// Wt float4 (A',B',Wz',0) at [l][d][j]; scales_tail=[1,4/3,3/4] folded.
// std identity: sqrt(max(0.25m^2,eps)) == max(0.5|m|,1e-3) (exact).
// mlp_b2 softmax-invariant -> dropped.
// R8 lesson: cross-block atomic bins + last-block readback corrupted output
// (G16) -> separate k_final kept; mid-role self-folds rather than reading
// another block's output.
// 128KB static LDS is gfx950-legal (learn_hip gemm_256sq_8phase uses it);
// 134 blocks < 256 CUs so 1-block/CU occupancy is free.
// Harness floor: ~41us 256MiB poison-fill (at HBM ceiling) + ~50us memops/iter.

typedef const float* fp;

// workspace layout (floats) -- offsets unchanged from R12; Wt/relT slots for
// layers 0/1 are now unused (mid-role self-computes them in LDS).
#define WS_WT     0        // only +32768.. used  (Wt2[d][j][c])
#define WS_RELT   49152    // only +12288.. used  (relT l=2)
#define WS_QW1    67584    // 8*64                query@mlp_W1[64:128]+mlp_b1
#define WS_Q2     68096    // 8*144*64 = 73728
#define WS_QW3    141824   // 8*12*64             Q3@lin_W2[0:64] + lin_b2
#define WS_SCORES 142592   // 8*1728
// total 156416 floats

// quad accumulate: d components x..w use weight float4s wa..wd (Wt cols A',B',Wz')
__device__ __forceinline__ void accq(float4 mv, float4 tv,
                                     float4 wa, float4 wb, float4 wc, float4 wd,
                                     float& acc){
  acc += mv.x*wa.x; acc += fabsf(mv.x)*wa.y; acc += tv.x*wa.z;
  acc += mv.y*wb.x; acc += fabsf(mv.y)*wb.y; acc += tv.y*wb.z;
  acc += mv.z*wc.x; acc += fabsf(mv.z)*wc.y; acc += tv.z*wc.z;
  acc += mv.w*wd.x; acc += fabsf(mv.w)*wd.y; acc += tv.w*wd.z;
}

// fold one Wt element (layer l, row-block d, col j, component c) from lin_W
__device__ __forceinline__ float foldWt(fp lin_W, int l, int d, int j, int c){
  fp W = lin_W + (size_t)l*832*64 + (64 + 12*d)*64 + j;   // rows stride 64
  float v = 0.f;
  if (c == 0){
    float w0 = W[0]   + (4.f/3.f)*W[64]  + 0.75f*W[128];
    float w1 = W[192] + (4.f/3.f)*W[256] + 0.75f*W[320];
    float w2 = W[384] + (4.f/3.f)*W[448] + 0.75f*W[512];
    v = 0.5f*w0 + 0.5f*(w1 + w2);        // A' = (A+Bc)/2
  } else if (c == 1){
    float w1 = W[192] + (4.f/3.f)*W[256] + 0.75f*W[320];
    float w2 = W[384] + (4.f/3.f)*W[448] + 0.75f*W[512];
    v = 0.5f*(w1 - w2);                  // B' = (A-Bc)/2
  } else if (c == 2){
    v = 0.5f*(W[576] + (4.f/3.f)*W[640] + 0.75f*W[704]);  // Wz' = 0.5*Wz
  }
  return v;
}

// blocks 0..29: pre-role (Wt2, relT2, QW1).  blocks 30..133: mid-role.
__global__ __launch_bounds__(768) void k_pre(fp indicator, fp query, fp lin_W,
                       fp lin_b, fp rel_W, fp rel_b, fp mlp_W1, fp mlp_b1,
                       float* ws){
  __shared__ float sWt[32768];              // 128KB: [l][d][j][c], l=0,1
  __shared__ float sC2[64], sC2W[64], sP1[64], sQ3[12][64];
  __shared__ __align__(16) float mP[64], tP[64];
  __shared__ __align__(16) float mL[12][64], tL[12][64];
  __shared__ __align__(16) float sRel0[64];
  __shared__ __align__(16) float sRel1[12][64];
  int tid = threadIdx.x;

  if (blockIdx.x < 30){
    // ---------------- pre-role ----------------
    int t = blockIdx.x*768 + tid;
    if (t < 16384){
      int g = 32768 + t;                    // Wt layer2 element
      int c = g & 3; int j = (g>>2)&63; int d = (g>>8)&63;
      ws[WS_WT + g] = foldWt(lin_W, 2, d, j, c);
    } else if (t < 22528){
      int e = 12288 + (t - 16384);          // relT l=2
      int d = e & 63; int j = (e>>6)%12; int b = (e/768)&7;
      float acc = rel_b[2*768 + j*64 + d];
      fp W = rel_W + (size_t)2*64*768 + j*64 + d;
      fp q = query + b*64;
      #pragma unroll 32
      for (int k=0;k<64;k++) acc += q[k] * W[k*768];
      ws[WS_RELT + e] = acc;
    } else if (t < 23040){
      int e = t - 22528; int b = e>>6; int j = e&63;
      float acc = mlp_b1[j];
      fp q = query + b*64;
      #pragma unroll 32
      for (int i=0;i<64;i++) acc += q[i] * mlp_W1[(64+i)*64 + j];
      ws[WS_QW1 + e] = acc;
    }
    return;
  }

  // ---------------- mid-role ----------------
  int mb = blockIdx.x - 30;
  int w = tid>>6, j = tid&63;
  bool isQ2 = mb < 96;
  int b  = isQ2 ? mb/12 : mb-96;
  int i0 = isQ2 ? mb%12 : 0;

  // A: fold Wt layers 0,1 into LDS (same fold arithmetic as k_pre1 -> bitwise id)
  for (int f = tid; f < 32768; f += 768){
    int c = f & 3; int jj = (f>>2)&63; int d = (f>>8)&63; int l = f>>14;
    sWt[f] = foldWt(lin_W, l, d, jj, c);
  }
  // B: relT layer1 (12x64 dots, one per thread) + relT layer0 row (b,i0)
  {
    int idx = tid>>6, d = tid&63;
    float acc = rel_b[768 + idx*64 + d];
    fp W = rel_W + (size_t)64*768 + idx*64 + d;
    fp q = query + b*64;
    #pragma unroll 32
    for (int k=0;k<64;k++) acc += q[k] * W[k*768];
    sRel1[idx][d] = acc;
  }
  if (isQ2 && tid < 64){
    float acc = rel_b[i0*64 + tid];
    fp W = rel_W + i0*64 + tid;
    fp q = query + b*64;
    #pragma unroll 32
    for (int k=0;k<64;k++) acc += q[k] * W[k*768];
    sRel0[tid] = acc;
  }
  __syncthreads();
  // phase 0: C2 (wave 0) | mP/tP precompute (wave 1, lane=d)
  if (w == 0){
    float acc = lin_b[j];                   // C2: layer0 const state
    #pragma unroll 8
    for (int d=0; d<64; d++) acc += 2e-3f * sWt[((d<<6)+j)*4 + 2];
    sC2[j] = fmaxf(acc, 0.f);               // 2e-3*Wz' == 1e-3*Wz (exact)
  } else if (w == 1 && isQ2){
    float m = indicator[j] * sRel0[j];
    mP[j] = m; tP[j] = fmaxf(fabsf(m), 2e-3f);
  }
  __syncthreads();
  // phase 1: C2W (wave 0) | P1 (wave 1)
  if (w == 0){
    float a2 = lin_b[64+j];                 // C2W = C2 @ lin_W1[0:64] + b1
    fp W1 = lin_W + 832*64;
    #pragma unroll 16
    for (int k=0;k<64;k++) a2 += sC2[k] * W1[k*64+j];
    sC2W[j] = a2;
  } else if (w == 1 && isQ2){
    const float4* W4 = (const float4*)sWt;  // layer0 Wt
    float acc = lin_b[j];
    #pragma unroll
    for (int dq=0; dq<16; dq++){
      float4 mv = ((const float4*)mP)[dq], tv = ((const float4*)tP)[dq];
      float4 wa = W4[(dq*4+0)*64+j], wb = W4[(dq*4+1)*64+j],
             wc = W4[(dq*4+2)*64+j], wd = W4[(dq*4+3)*64+j];
      accq(mv,tv,wa,wb,wc,wd,acc);
    }
    sP1[j] = fmaxf(acc, 0.f);
  }
  __syncthreads();
  // phase 2: per-wave layer1 m/t precompute (lane=d)
  {
    float s = isQ2 ? sP1[j] : sC2[j];
    float m = s * sRel1[w][j];
    mL[w][j] = m; tL[w][j] = fmaxf(fabsf(m), 2e-3f);
  }
  __syncthreads();
  // phase 3: Q2 / Q3+QW3
  const float4* W4 = (const float4*)(sWt + 16384);  // layer1 Wt
  float acc = sC2W[j];
  #pragma unroll
  for (int dq=0; dq<16; dq++){
    float4 mv = ((const float4*)mL[w])[dq], tv = ((const float4*)tL[w])[dq];
    float4 wa = W4[(dq*4+0)*64+j], wb = W4[(dq*4+1)*64+j],
           wc = W4[(dq*4+2)*64+j], wd = W4[(dq*4+3)*64+j];
    accq(mv,tv,wa,wb,wc,wd,acc);
  }
  if (isQ2){
    ws[WS_Q2 + ((b*12+i0)*12+w)*64 + j] = fmaxf(acc, 0.f);
  } else {
    sQ3[w][j] = fmaxf(acc, 0.f);
    __syncthreads();                        // block-uniform branch
    fp W2 = lin_W + 2*832*64;               // layer2, rows 0..63
    float a = lin_b[128+j];
    #pragma unroll 16
    for (int k=0;k<64;k++) a += sQ3[w][k]*W2[k*64+j];
    ws[WS_QW3 + (b*12+w)*64 + j] = a;
  }
}

// 864 blocks x 256 thr; wave = 4 rules (b,i0,i2 shared, i1 = i1b..i1b+3).
// Wt2 staged through LDS in 4x16KB chunks; m/t hoisted per-wave into LDS.
__global__ __launch_bounds__(256) void k_score(fp mlp_W1, fp mlp_W2, float* ws){
  __shared__ float wt_s[4096];              // 16 KB chunk
  __shared__ float fin[4][4][64];
  __shared__ __align__(16) float m_s[4][4][64];   // [wave][rule][d]
  __shared__ __align__(16) float t_s[4][4][64];
  int tid = threadIdx.x, w = tid>>6, j = tid&63;
  int wave = blockIdx.x*4 + w;              // 0..3455
  int b = blockIdx.x/108;                   // block-uniform (432 waves/b)
  int rem = wave%432;
  int i0 = rem/36; int t36 = rem%36;
  int i2 = t36/3;  int i1b = (t36%3)*4;
  // precompute m/t: lane j = d index; one mul+max covers 64 d's per rule
  {
    float rl = ws[WS_RELT + 12288 + (b*12+i2)*64 + j];
    #pragma unroll
    for (int r=0;r<4;r++){
      float qv = ws[WS_Q2 + ((b*12+i0)*12 + i1b + r)*64 + j];
      float m = qv*rl;
      m_s[w][r][j] = m;
      t_s[w][r][j] = fmaxf(fabsf(m), 2e-3f);
    }
  }
  float a0 = ws[WS_QW3 + (b*12+i2)*64 + j];
  float acc[4] = {a0, a0, a0, a0};
  const float4* Wt2 = (const float4*)(ws + WS_WT + 32768);
  for (int ch=0; ch<4; ch++){
    __syncthreads();                        // protect previous chunk (+mt vis)
    {
      const float4* src = Wt2 + ch*1024;
      float4* dst = (float4*)wt_s;
      #pragma unroll
      for (int k=0; k<4; k++) dst[tid + k*256] = src[tid + k*256];
    }
    __syncthreads();
    #pragma unroll
    for (int dq=0; dq<4; dq++){
      int dc = ch*4 + dq;
      const float4* wl = (const float4*)wt_s + dq*256 + j;
      float4 wa = wl[0], wb = wl[64], wc = wl[128], wd = wl[192];
      #pragma unroll
      for (int r=0;r<4;r++){
        float4 mv = ((const float4*)m_s[w][r])[dc];   // broadcast reads
        float4 tv = ((const float4*)t_s[w][r])[dc];
        accq(mv,tv,wa,wb,wc,wd,acc[r]);
      }
    }
  }
  __syncthreads();
  fin[w][0][j]=fmaxf(acc[0],0.f); fin[w][1][j]=fmaxf(acc[1],0.f);
  fin[w][2][j]=fmaxf(acc[2],0.f); fin[w][3][j]=fmaxf(acc[3],0.f);
  __syncthreads();
  float qw = ws[WS_QW1 + b*64 + j];
  float w2v = mlp_W2[j];
  float h0=qw, h1=qw, h2=qw, h3=qw;
  #pragma unroll 8
  for (int i=0;i<64;i++){
    float wv = mlp_W1[i*64+j];              // rows 0..63, shared by 4 rules
    h0 += fin[w][0][i]*wv; h1 += fin[w][1][i]*wv;
    h2 += fin[w][2][i]*wv; h3 += fin[w][3][i]*wv;
  }
  float s0=fmaxf(h0,0.f)*w2v, s1=fmaxf(h1,0.f)*w2v;
  float s2=fmaxf(h2,0.f)*w2v, s3=fmaxf(h3,0.f)*w2v;
  #pragma unroll
  for (int off=32; off>0; off>>=1){
    s0 += __shfl_down(s0, off, 64); s1 += __shfl_down(s1, off, 64);
    s2 += __shfl_down(s2, off, 64); s3 += __shfl_down(s3, off, 64);
  }
  if (j == 0){
    int rbase = i0*144 + i1b*12 + i2;
    float* S = ws + WS_SCORES + b*1728 + rbase;
    S[0] = s0; S[12] = s1; S[24] = s2; S[36] = s3;
  }
}

__global__ void k_final(fp relation_emb, float* ws, float* out){
  int b = blockIdx.x, tid = threadIdx.x;           // 256 threads = 4 waves
  int w = tid>>6, lane = tid&63;
  __shared__ float se[1728];
  __shared__ float wred[4];
  __shared__ float pb[36][4];
  __shared__ float bins[36];
  const float* sc = ws + WS_SCORES + b*1728;
  float mx = -1e30f;
  for (int r=tid; r<1728; r+=256){ float v = sc[r]; se[r] = v; mx = fmaxf(mx, v); }
  #pragma unroll
  for (int off=32; off>0; off>>=1) mx = fmaxf(mx, __shfl_xor(mx, off, 64));
  if (lane == 0) wred[w] = mx;
  __syncthreads();
  mx = fmaxf(fmaxf(wred[0],wred[1]), fmaxf(wred[2],wred[3]));
  __syncthreads();                          // protect wred reuse
  float ts = 0.f;
  for (int r=tid; r<1728; r+=256){ float e = __expf(se[r]-mx); se[r] = e; ts += e; }
  #pragma unroll
  for (int off=32; off>0; off>>=1) ts += __shfl_xor(ts, off, 64);
  if (lane == 0) wred[w] = ts;
  __syncthreads();
  float tot = (wred[0]+wred[1]) + (wred[2]+wred[3]);
  if (tid < 144){                           // 4 partials per bin
    int bin = tid>>2, q = tid&3;            // bin = h*12+jj
    int h = bin/12, jj = bin%12;
    float a = 0.f;
    if (h == 0){
      const float* p = se + jj*144 + q*36;
      #pragma unroll 4
      for (int k=0;k<36;k++) a += p[k];
    } else if (h == 1){
      for (int t=q*36; t<q*36+36; t++) a += se[(t/12)*144 + jj*12 + (t%12)];
    } else {
      for (int t=q*36; t<q*36+36; t++) a += se[(t/12)*144 + (t%12)*12 + jj];
    }
    pb[bin][q] = a;
  }
  __syncthreads();
  if (tid < 36) bins[tid] = (pb[tid][0]+pb[tid][1]) + (pb[tid][2]+pb[tid][3]);
  __syncthreads();
  if (tid < 192){
    int h = tid>>6, d = tid&63;
    float acc = 0.f;
    #pragma unroll
    for (int jj=0; jj<12; jj++) acc += bins[h*12+jj] * relation_emb[jj*64+d];
    out[b*192 + tid] = acc/tot;                    // subgoals, f32
  }
  if (tid >= 192 && tid < 195){
    out[1536 + b*3 + (tid-192)] = 1.0f;            // masks = True, f32
  }
}

extern "C" void kernel_launch(void* const* d_in, const int* in_sizes, int n_in,
                              void* d_out, int out_size, void* d_ws, size_t ws_size,
                              hipStream_t stream){
  fp query        = (fp)d_in[0];
  fp relation_emb = (fp)d_in[1];
  fp indicator    = (fp)d_in[2];
  fp rel_W        = (fp)d_in[3];
  fp rel_b        = (fp)d_in[4];
  fp lin_W        = (fp)d_in[5];
  fp lin_b        = (fp)d_in[6];
  fp mlp_W1       = (fp)d_in[7];
  fp mlp_b1       = (fp)d_in[8];
  fp mlp_W2       = (fp)d_in[9];
  float* ws = (float*)d_ws;
  float* out = (float*)d_out;

  k_pre  <<<134, 768, 0, stream>>>(indicator, query, lin_W, lin_b, rel_W, rel_b,
                                   mlp_W1, mlp_b1, ws);
  k_score<<<864, 256, 0, stream>>>(mlp_W1, mlp_W2, ws);
  k_final<<<8,   256, 0, stream>>>(relation_emb, ws, out);
}

// Round 4
// 114.654 us; speedup vs baseline: 1.2662x; 1.2662x over previous
//
#include <hip/hip_runtime.h>
#include <hip/hip_bf16.h>

// RuleNBFNet: B=8, D=64, H=3, R2=12, Rn=1728.  Inputs f32, output f32.
// 4-kernel pipeline: k_pre1 (Wt,relT,QW1) -> k_mid (Q2,QW3) -> k_score -> k_final.
// R13 lesson (REVERTED): fusing pre+mid duplicated the Wt0/1 fold across 104
// blocks -> 56us latency-bound kernel (80 GB/s, VALU 6%).  But it localized the
// cost: k_pre1+k_mid ~20-27us of the ~24us controllable time, latency-bound on
// cold HBM misses (poison fill wipes L2/L3 every iter; ~900cyc/miss at ~1
// wave/SIMD).
// R14: k_pre1 restructured for latency tolerance:
//   - Wt fold: 48 blocks stage contiguous 12KB lin_W row-spans into LDS
//     (3 coalesced float4 loads/thread = one miss window), fold from LDS.
//     Same arithmetic -> Wt bitwise identical.
//   - relT / QW1: 4-way K-split (16 cold loads/thread, LDS reduce) ->
//     4x fewer exposed miss windows + more waves.  Reassociates dots at
//     16-elem boundaries (few-ulp; harness passed at 4.9e-4 before).
// Feature algebra: m=q*rel, p=max(m,0), n=min(m,0):
//   0.5m*W0 + p*W1 + n*W2 + max(0.5|m|,1e-3)*W3
//     = p*A + n*Bc + max(|m|,2e-3)*Wz'   with A=0.5W0+W1, Bc=0.5W0+W2, Wz'=0.5W3
// R11 refold: p*A + n*Bc = m*A' + |m|*B'  with A'=(A+Bc)/2, B'=(A-Bc)/2.
// R12: m,t=max(|m|,2e-3) lane-invariant -> hoisted per-wave into LDS;
//   inner loop = 3 fma per (rule,d) + broadcast ds_read_b128.
// Wt float4 (A',B',Wz',0) at [l][d][j]; scales_tail=[1,4/3,3/4] folded.
// std identity: sqrt(max(0.25m^2,eps)) == max(0.5|m|,1e-3) (exact).
// mlp_b2 softmax-invariant -> dropped.
// R8 lesson: cross-block atomic bins + readback corrupted output (G16) ->
// separate k_final kept.
// R10 lesson: 16KB LDS chunks in k_score; R12 mt arrays on top.
// Harness floor: ~41us 256MiB poison-fill (at HBM ceiling) + ~50us memops/iter.

typedef const float* fp;

// workspace layout (floats)
#define WS_WT     0        // 3*64*64*4 = 49152   Wt[l][d][j][c]
#define WS_RELT   49152    // 3*8*12*64 = 18432   relT[l][b][j][d]
#define WS_QW1    67584    // 8*64                query@mlp_W1[64:128]+mlp_b1
#define WS_Q2     68096    // 8*144*64 = 73728
#define WS_QW3    141824   // 8*12*64             Q3@lin_W2[0:64] + lin_b2
#define WS_SCORES 142592   // 8*1728
// total 156416 floats

// quad accumulate: d components x..w use weight float4s wa..wd (Wt cols A',B',Wz')
__device__ __forceinline__ void accq(float4 mv, float4 tv,
                                     float4 wa, float4 wb, float4 wc, float4 wd,
                                     float& acc){
  acc += mv.x*wa.x; acc += fabsf(mv.x)*wa.y; acc += tv.x*wa.z;
  acc += mv.y*wb.x; acc += fabsf(mv.y)*wb.y; acc += tv.y*wb.z;
  acc += mv.z*wc.x; acc += fabsf(mv.z)*wc.y; acc += tv.z*wc.z;
  acc += mv.w*wd.x; acc += fabsf(mv.w)*wd.y; acc += tv.w*wd.z;
}

// blocks 0..47: Wt fold (LDS-staged).  48..335: relT (4-way K-split).
// 336..343: QW1 (4-way K-split).
__global__ __launch_bounds__(256) void k_pre1(fp lin_W, fp query, fp rel_W,
                       fp rel_b, fp mlp_W1, fp mlp_b1, float* ws){
  __shared__ float sW[3072];                // 12KB: 48 lin_W rows
  __shared__ float part[4][64];
  int bi = blockIdx.x, tid = threadIdx.x;

  if (bi < 48){
    // ---- Wt fold: l = bi/16, d0 = (bi%16)*4; rows 64+12*d0 .. +48 ----
    int l = bi>>4, d0 = (bi&15)*4;
    fp src = lin_W + (size_t)l*832*64 + (size_t)(64 + 12*d0)*64;  // 3072 floats
    float4* s4 = (float4*)sW;
    const float4* g4 = (const float4*)src;
    s4[tid] = g4[tid]; s4[tid+256] = g4[tid+256]; s4[tid+512] = g4[tid+512];
    __syncthreads();
    int c = tid&3, j = tid>>2;              // tid = j*4+c  (coalesced writes)
    #pragma unroll
    for (int dd=0; dd<4; dd++){
      const float* W = sW + dd*768 + j;     // 12 rows of 64, row stride 64
      float v = 0.f;
      if (c == 0){
        float w0 = W[0]   + (4.f/3.f)*W[64]  + 0.75f*W[128];
        float w1 = W[192] + (4.f/3.f)*W[256] + 0.75f*W[320];
        float w2 = W[384] + (4.f/3.f)*W[448] + 0.75f*W[512];
        v = 0.5f*w0 + 0.5f*(w1 + w2);       // A' = (A+Bc)/2
      } else if (c == 1){
        float w1 = W[192] + (4.f/3.f)*W[256] + 0.75f*W[320];
        float w2 = W[384] + (4.f/3.f)*W[448] + 0.75f*W[512];
        v = 0.5f*(w1 - w2);                 // B' = (A-Bc)/2
      } else if (c == 2){
        v = 0.5f*(W[576] + (4.f/3.f)*W[640] + 0.75f*W[704]); // Wz' = 0.5*Wz
      }
      ws[WS_WT + l*16384 + (d0+dd)*256 + tid] = v;
    }
  } else if (bi < 336){
    // ---- relT[l][b][jj][d]: 288 blocks, one (l,b,jj) each; 4-way K-split ----
    int idx = bi - 48;
    int l = idx/96; int rem = idx%96; int b = rem/12; int jj = rem%12;
    int d = tid&63, kc = tid>>6;
    fp W = rel_W + (size_t)l*64*768 + (size_t)(kc*16)*768 + jj*64 + d;
    fp q = query + b*64 + kc*16;
    float acc = (kc == 0) ? rel_b[l*768 + jj*64 + d] : 0.f;
    #pragma unroll
    for (int k=0;k<16;k++) acc += q[k] * W[k*768];
    part[kc][d] = acc;
    __syncthreads();
    if (tid < 64){
      float v = ((part[0][tid] + part[1][tid]) + part[2][tid]) + part[3][tid];
      ws[WS_RELT + l*6144 + b*768 + jj*64 + tid] = v;
    }
  } else {
    // ---- QW1[b][j]: 8 blocks, 4-way K-split ----
    int b = bi - 336;
    int j = tid&63, kc = tid>>6;
    float acc = (kc == 0) ? mlp_b1[j] : 0.f;
    fp q = query + b*64 + kc*16;
    #pragma unroll
    for (int i=0;i<16;i++) acc += q[i] * mlp_W1[(64 + kc*16 + i)*64 + j];
    part[kc][j] = acc;
    __syncthreads();
    if (tid < 64){
      float v = ((part[0][tid] + part[1][tid]) + part[2][tid]) + part[3][tid];
      ws[WS_QW1 + b*64 + tid] = v;
    }
  }
}

// blocks 0..95: (b,i0) -> Q2[b,i0,0..11]; blocks 96..103: b -> QW3[b,0..11]
__global__ void k_mid(fp indicator, fp lin_W, fp lin_b, float* ws){
  __shared__ float sC2[64], sC2W[64], sP1[64], sQ3[12][64];
  __shared__ __align__(16) float mP[64], tP[64];        // P1-pass m/t
  __shared__ __align__(16) float mL[12][64], tL[12][64];// layer1 per-wave m/t
  int tid = threadIdx.x;                    // 768 threads = 12 waves
  int w = tid>>6, j = tid&63;
  bool isQ2 = blockIdx.x < 96;
  int b  = isQ2 ? blockIdx.x/12 : blockIdx.x-96;
  int i0 = isQ2 ? blockIdx.x%12 : 0;
  // phase 0: C2 (wave 0) | mP/tP precompute (wave 1, lane=d)
  if (w == 0){
    float acc = lin_b[j];                   // C2: layer0 const state
    #pragma unroll 8
    for (int d=0; d<64; d++) acc += 2e-3f * ws[WS_WT + ((d<<6)+j)*4 + 2];
    sC2[j] = fmaxf(acc, 0.f);               // 2e-3*Wz' == 1e-3*Wz (exact)
  } else if (w == 1 && isQ2){
    const float* rel = ws + WS_RELT + (b*12+i0)*64;        // l=0
    float m = indicator[j] * rel[j];
    mP[j] = m; tP[j] = fmaxf(fabsf(m), 2e-3f);
  }
  __syncthreads();
  // phase 1: C2W (wave 0) | P1 (wave 1)
  if (w == 0){
    float a2 = lin_b[64+j];                 // C2W = C2 @ lin_W1[0:64] + b1
    fp W1 = lin_W + 832*64;
    #pragma unroll 16
    for (int k=0;k<64;k++) a2 += sC2[k] * W1[k*64+j];
    sC2W[j] = a2;
  } else if (w == 1 && isQ2){
    const float4* W4 = (const float4*)(ws + WS_WT);        // layer0 Wt
    float acc = lin_b[j];
    #pragma unroll
    for (int dq=0; dq<16; dq++){
      float4 mv = ((const float4*)mP)[dq], tv = ((const float4*)tP)[dq];
      float4 wa = W4[(dq*4+0)*64+j], wb = W4[(dq*4+1)*64+j],
             wc = W4[(dq*4+2)*64+j], wd = W4[(dq*4+3)*64+j];
      accq(mv,tv,wa,wb,wc,wd,acc);
    }
    sP1[j] = fmaxf(acc, 0.f);
  }
  __syncthreads();
  // phase 2: per-wave layer1 m/t precompute (lane=d)
  {
    const float* rel = ws + WS_RELT + 6144 + (b*12+w)*64;  // l=1, idx=w
    float s = isQ2 ? sP1[j] : sC2[j];
    float m = s * rel[j];
    mL[w][j] = m; tL[w][j] = fmaxf(fabsf(m), 2e-3f);
  }
  __syncthreads();
  // phase 3: Q2 / Q3+QW3
  const float4* W4 = (const float4*)(ws + WS_WT + 16384);  // layer1 Wt
  float acc = sC2W[j];
  #pragma unroll
  for (int dq=0; dq<16; dq++){
    float4 mv = ((const float4*)mL[w])[dq], tv = ((const float4*)tL[w])[dq];
    float4 wa = W4[(dq*4+0)*64+j], wb = W4[(dq*4+1)*64+j],
           wc = W4[(dq*4+2)*64+j], wd = W4[(dq*4+3)*64+j];
    accq(mv,tv,wa,wb,wc,wd,acc);
  }
  if (isQ2){
    ws[WS_Q2 + ((b*12+i0)*12+w)*64 + j] = fmaxf(acc, 0.f);
  } else {
    sQ3[w][j] = fmaxf(acc, 0.f);
    __syncthreads();                        // block-uniform branch
    fp W2 = lin_W + 2*832*64;               // layer2, rows 0..63
    float a = lin_b[128+j];
    #pragma unroll 16
    for (int k=0;k<64;k++) a += sQ3[w][k]*W2[k*64+j];
    ws[WS_QW3 + (b*12+w)*64 + j] = a;
  }
}

// 864 blocks x 256 thr; wave = 4 rules (b,i0,i2 shared, i1 = i1b..i1b+3).
// Wt2 staged through LDS in 4x16KB chunks; m/t hoisted per-wave into LDS.
__global__ __launch_bounds__(256) void k_score(fp mlp_W1, fp mlp_W2, float* ws){
  __shared__ float wt_s[4096];              // 16 KB chunk
  __shared__ float fin[4][4][64];
  __shared__ __align__(16) float m_s[4][4][64];   // [wave][rule][d]
  __shared__ __align__(16) float t_s[4][4][64];
  int tid = threadIdx.x, w = tid>>6, j = tid&63;
  int wave = blockIdx.x*4 + w;              // 0..3455
  int b = blockIdx.x/108;                   // block-uniform (432 waves/b)
  int rem = wave%432;
  int i0 = rem/36; int t36 = rem%36;
  int i2 = t36/3;  int i1b = (t36%3)*4;
  // precompute m/t: lane j = d index; one mul+max covers 64 d's per rule
  {
    float rl = ws[WS_RELT + 12288 + (b*12+i2)*64 + j];
    #pragma unroll
    for (int r=0;r<4;r++){
      float qv = ws[WS_Q2 + ((b*12+i0)*12 + i1b + r)*64 + j];
      float m = qv*rl;
      m_s[w][r][j] = m;
      t_s[w][r][j] = fmaxf(fabsf(m), 2e-3f);
    }
  }
  float a0 = ws[WS_QW3 + (b*12+i2)*64 + j];
  float acc[4] = {a0, a0, a0, a0};
  const float4* Wt2 = (const float4*)(ws + WS_WT + 32768);
  for (int ch=0; ch<4; ch++){
    __syncthreads();                        // protect previous chunk (+mt vis)
    {
      const float4* src = Wt2 + ch*1024;
      float4* dst = (float4*)wt_s;
      #pragma unroll
      for (int k=0; k<4; k++) dst[tid + k*256] = src[tid + k*256];
    }
    __syncthreads();
    #pragma unroll
    for (int dq=0; dq<4; dq++){
      int dc = ch*4 + dq;
      const float4* wl = (const float4*)wt_s + dq*256 + j;
      float4 wa = wl[0], wb = wl[64], wc = wl[128], wd = wl[192];
      #pragma unroll
      for (int r=0;r<4;r++){
        float4 mv = ((const float4*)m_s[w][r])[dc];   // broadcast reads
        float4 tv = ((const float4*)t_s[w][r])[dc];
        accq(mv,tv,wa,wb,wc,wd,acc[r]);
      }
    }
  }
  __syncthreads();
  fin[w][0][j]=fmaxf(acc[0],0.f); fin[w][1][j]=fmaxf(acc[1],0.f);
  fin[w][2][j]=fmaxf(acc[2],0.f); fin[w][3][j]=fmaxf(acc[3],0.f);
  __syncthreads();
  float qw = ws[WS_QW1 + b*64 + j];
  float w2v = mlp_W2[j];
  float h0=qw, h1=qw, h2=qw, h3=qw;
  #pragma unroll 8
  for (int i=0;i<64;i++){
    float wv = mlp_W1[i*64+j];              // rows 0..63, shared by 4 rules
    h0 += fin[w][0][i]*wv; h1 += fin[w][1][i]*wv;
    h2 += fin[w][2][i]*wv; h3 += fin[w][3][i]*wv;
  }
  float s0=fmaxf(h0,0.f)*w2v, s1=fmaxf(h1,0.f)*w2v;
  float s2=fmaxf(h2,0.f)*w2v, s3=fmaxf(h3,0.f)*w2v;
  #pragma unroll
  for (int off=32; off>0; off>>=1){
    s0 += __shfl_down(s0, off, 64); s1 += __shfl_down(s1, off, 64);
    s2 += __shfl_down(s2, off, 64); s3 += __shfl_down(s3, off, 64);
  }
  if (j == 0){
    int rbase = i0*144 + i1b*12 + i2;
    float* S = ws + WS_SCORES + b*1728 + rbase;
    S[0] = s0; S[12] = s1; S[24] = s2; S[36] = s3;
  }
}

__global__ void k_final(fp relation_emb, float* ws, float* out){
  int b = blockIdx.x, tid = threadIdx.x;           // 256 threads = 4 waves
  int w = tid>>6, lane = tid&63;
  __shared__ float se[1728];
  __shared__ float wred[4];
  __shared__ float pb[36][4];
  __shared__ float bins[36];
  const float* sc = ws + WS_SCORES + b*1728;
  float mx = -1e30f;
  for (int r=tid; r<1728; r+=256){ float v = sc[r]; se[r] = v; mx = fmaxf(mx, v); }
  #pragma unroll
  for (int off=32; off>0; off>>=1) mx = fmaxf(mx, __shfl_xor(mx, off, 64));
  if (lane == 0) wred[w] = mx;
  __syncthreads();
  mx = fmaxf(fmaxf(wred[0],wred[1]), fmaxf(wred[2],wred[3]));
  __syncthreads();                          // protect wred reuse
  float ts = 0.f;
  for (int r=tid; r<1728; r+=256){ float e = __expf(se[r]-mx); se[r] = e; ts += e; }
  #pragma unroll
  for (int off=32; off>0; off>>=1) ts += __shfl_xor(ts, off, 64);
  if (lane == 0) wred[w] = ts;
  __syncthreads();
  float tot = (wred[0]+wred[1]) + (wred[2]+wred[3]);
  if (tid < 144){                           // 4 partials per bin
    int bin = tid>>2, q = tid&3;            // bin = h*12+jj
    int h = bin/12, jj = bin%12;
    float a = 0.f;
    if (h == 0){
      const float* p = se + jj*144 + q*36;
      #pragma unroll 4
      for (int k=0;k<36;k++) a += p[k];
    } else if (h == 1){
      for (int t=q*36; t<q*36+36; t++) a += se[(t/12)*144 + jj*12 + (t%12)];
    } else {
      for (int t=q*36; t<q*36+36; t++) a += se[(t/12)*144 + (t%12)*12 + jj];
    }
    pb[bin][q] = a;
  }
  __syncthreads();
  if (tid < 36) bins[tid] = (pb[tid][0]+pb[tid][1]) + (pb[tid][2]+pb[tid][3]);
  __syncthreads();
  if (tid < 192){
    int h = tid>>6, d = tid&63;
    float acc = 0.f;
    #pragma unroll
    for (int jj=0; jj<12; jj++) acc += bins[h*12+jj] * relation_emb[jj*64+d];
    out[b*192 + tid] = acc/tot;                    // subgoals, f32
  }
  if (tid >= 192 && tid < 195){
    out[1536 + b*3 + (tid-192)] = 1.0f;            // masks = True, f32
  }
}

extern "C" void kernel_launch(void* const* d_in, const int* in_sizes, int n_in,
                              void* d_out, int out_size, void* d_ws, size_t ws_size,
                              hipStream_t stream){
  fp query        = (fp)d_in[0];
  fp relation_emb = (fp)d_in[1];
  fp indicator    = (fp)d_in[2];
  fp rel_W        = (fp)d_in[3];
  fp rel_b        = (fp)d_in[4];
  fp lin_W        = (fp)d_in[5];
  fp lin_b        = (fp)d_in[6];
  fp mlp_W1       = (fp)d_in[7];
  fp mlp_b1       = (fp)d_in[8];
  fp mlp_W2       = (fp)d_in[9];
  float* ws = (float*)d_ws;
  float* out = (float*)d_out;

  k_pre1 <<<344, 256, 0, stream>>>(lin_W, query, rel_W, rel_b, mlp_W1, mlp_b1, ws);
  k_mid  <<<104, 768, 0, stream>>>(indicator, lin_W, lin_b, ws);
  k_score<<<864, 256, 0, stream>>>(mlp_W1, mlp_W2, ws);
  k_final<<<8,   256, 0, stream>>>(relation_emb, ws, out);
}